// Round 10
// baseline (11017.438 us; speedup 1.0000x reference)
//
#include <hip/hip_runtime.h>

#define NIN  512
#define NREC 2048
#define NOUT 128
#define BB   64
#define TT   250

// OUTPUTS ARE FLOAT32 (established R9 probe). Semantics: JAX text.
// ---- d_ws layout (31.4 MB total; 34.5 MB verified safe in R2) ----
#define OFF_WRT  0UL          // f32 W_r^T [n][m]      16,777,216
#define OFF_DB   16777216UL   // u8  delays [n][m]      4,194,304
#define OFF_WIT  20971520UL   // f32 W_i^T [i][m]       4,194,304
#define OFF_WOT  25165824UL   // f32 W_o^T [n][o]       1,048,576
#define OFF_MASK 26214400UL   // u32 masks [t*64+b][64] 4,096,000
#define OFF_G    30310400UL   // f64 g[b][n]            1,048,576

// Delay element may be int32 0..4 (per reference) or fp32-encoded.
__device__ __forceinline__ int decode_delay(int v) {
    if (v >= 0 && v <= 4) return v;
    const float f = __int_as_float(v);
    if (f >= 0.5f && f <= 4.5f) return (int)(f + 0.5f);
    return 0;
}
__device__ __forceinline__ int delay_like(int v) {
    if (v >= 0 && v <= 4) return 1;
    const float f = __int_as_float(v);
    return (f >= 0.5f && f <= 4.5f) ? 1 : 0;
}

// Stage transposed weights + packed delays. Sniffs which of the two
// 4,194,304-element inputs is delays vs W_r (verified working in R6).
__global__ __launch_bounds__(256) void k_prep(
    const void* __restrict__ c4A, const void* __restrict__ c4B,
    const float* __restrict__ Wi, const float* __restrict__ Wo,
    float* __restrict__ WrT, unsigned char* __restrict__ dBp,
    float* __restrict__ WiT, float* __restrict__ WoT)
{
    const int* iA = (const int*)c4A;
    const int* iB = (const int*)c4B;
    int cntA = 0, cntB = 0;
    for (int j = 0; j < 64; ++j) { cntA += delay_like(iA[j]); cntB += delay_like(iB[j]); }
    const int*   dl = (cntA >= cntB) ? iA : iB;
    const float* Wr = (cntA >= cntB) ? (const float*)c4B : (const float*)c4A;

    const int idx = blockIdx.x * 256 + threadIdx.x;
    if (idx < NREC * NREC) {
        const int n = idx >> 11, m = idx & 2047;
        WrT[idx] = Wr[(size_t)m * NREC + n];                 // W_rT[n][m] = W_r[m][n]
        dBp[idx] = (unsigned char)decode_delay(dl[idx]);     // delays[n][m] natural
    }
    if (idx < NIN * NREC) {
        const int i = idx >> 11, m = idx & 2047;
        WiT[idx] = Wi[(size_t)m * NIN + i];                  // W_iT[i][m]
    }
    if (idx < NREC * NOUT) {
        const int n = idx >> 7, o = idx & 127;
        WoT[idx] = Wo[(size_t)o * NREC + n];                 // W_oT[n][o]
    }
}

// Main recurrence in FP64. One block per batch element, 1024 threads x 2
// neurons. Register delay ring (4 slots, rotated; post-rotate slot d-1 =
// delivery at t+d). Spikes via __ballot. Machinery bit-verified R2≡R3≡R4≡R6.
__global__ __launch_bounds__(1024) void k_main(
    const float* __restrict__ x,
    const float* __restrict__ WrT, const unsigned char* __restrict__ dBp,
    const float* __restrict__ WiT,
    const float* __restrict__ Br,
    const float* __restrict__ tau_rec, const float* __restrict__ tau_out,
    const float* __restrict__ thr_rec,
    unsigned* __restrict__ spikeMask, double* __restrict__ g)
{
    __shared__ unsigned lmask[64];      // recurrent spike bits (2048)
    __shared__ unsigned imask[16];      // input spike bits (512)
    const int b   = blockIdx.x;
    const int tid = threadIdx.x;

    const double rec_c = exp(-0.01 / (double)tau_rec[0]);   // DT*10 = 0.01
    const double out_c = exp(-0.01 / (double)tau_out[0]);
    const double thr   = (double)thr_rec[0];
    const double brA   = (double)Br[tid];
    const double brB   = (double)Br[tid + 1024];
    double memA = 0.0, memB = 0.0, gA = 0.0, gB = 0.0;
    double a0 = 0.0, a1 = 0.0, a2 = 0.0, a3 = 0.0;   // ring, neuron tid
    double b0 = 0.0, b1 = 0.0, b2 = 0.0, b3 = 0.0;   // ring, neuron tid+1024

    const float* xb = x + (size_t)b * NIN * TT;      // x[b][i][t]

    for (int t = 0; t < TT; ++t) {
        // consume current scheduled for this step, rotate ring
        double curA = a0; a0 = a1; a1 = a2; a2 = a3; a3 = 0.0;
        double curB = b0; b0 = b1; b1 = b2; b2 = b3; b3 = 0.0;

        // ballot input spikes: waves 0..7 cover i = tid in [0,512)
        if (tid < 512) {
            const float xv = xb[(size_t)tid * TT + t];
            unsigned long long m = __ballot(xv != 0.f);
            if ((tid & 63) == 0) {
                const int w = tid >> 6;
                imask[2 * w]     = (unsigned)(m & 0xFFFFFFFFu);
                imask[2 * w + 1] = (unsigned)(m >> 32);
            }
        }
        __syncthreads();

        // input current: sum of W_i^T rows of active channels (coalesced)
        for (int wd = 0; wd < 16; ++wd) {
            unsigned bits = imask[wd];
            while (bits) {
                const int i = wd * 32 + __ffs(bits) - 1;
                bits &= bits - 1;
                const float* wrow = WiT + (size_t)i * NREC;
                curA += (double)wrow[tid];
                curB += (double)wrow[tid + 1024];
            }
        }
        curA += brA; curB += brB;

        // LIF update + spike + soft reset
        memA = memA * rec_c + curA;
        memB = memB * rec_c + curB;
        const bool zA = (memA - thr) > 0.0;
        const bool zB = (memB - thr) > 0.0;
        if (zA) memA -= thr;
        if (zB) memB -= thr;

        // output Horner per neuron
        gA = gA * out_c + (zA ? 1.0 : 0.0);
        gB = gB * out_c + (zB ? 1.0 : 0.0);

        // publish spike bits (wave w covers neurons [64w, 64w+64))
        unsigned long long mA = __ballot(zA);
        unsigned long long mB = __ballot(zB);
        const int w = tid >> 6;
        if ((tid & 63) == 0) {
            const unsigned w0 = (unsigned)(mA & 0xFFFFFFFFu), w1 = (unsigned)(mA >> 32);
            const unsigned v0 = (unsigned)(mB & 0xFFFFFFFFu), v1 = (unsigned)(mB >> 32);
            lmask[2 * w] = w0;      lmask[2 * w + 1] = w1;
            lmask[32 + 2 * w] = v0; lmask[32 + 2 * w + 1] = v1;
            unsigned* gm = spikeMask + (size_t)(t * BB + b) * 64;
            gm[2 * w] = w0;      gm[2 * w + 1] = w1;
            gm[32 + 2 * w] = v0; gm[32 + 2 * w + 1] = v1;
        }
        __syncthreads();

        // scatter spikes (JAX-text semantics): spiker n, post m=tid:
        //   weight W_r[m][n] = WrT[n][m] (coalesced), delay delays[n][m]
        // delay d -> post-rotate slot d-1. (t > d gate <=> drop t'=0 spikes)
        if (t > 0) {
            for (int wd = 0; wd < 64; ++wd) {
                unsigned bits = lmask[wd];
                while (bits) {
                    const int n = wd * 32 + __ffs(bits) - 1;
                    bits &= bits - 1;
                    const size_t roff = (size_t)n * NREC;
                    const double wA = (double)WrT[roff + tid];
                    const double wB = (double)WrT[roff + tid + 1024];
                    const int dA = dBp[roff + tid];
                    const int dV = dBp[roff + tid + 1024];
                    a0 += (dA == 1) ? wA : 0.0;
                    a1 += (dA == 2) ? wA : 0.0;
                    a2 += (dA == 3) ? wA : 0.0;
                    a3 += (dA == 4) ? wA : 0.0;
                    b0 += (dV == 1) ? wB : 0.0;
                    b1 += (dV == 2) ? wB : 0.0;
                    b2 += (dV == 3) ? wB : 0.0;
                    b3 += (dV == 4) ? wB : 0.0;
                }
            }
        }
        __syncthreads();
    }

    g[(size_t)b * NREC + tid]        = gA;
    g[(size_t)b * NREC + tid + 1024] = gB;
}

// mem_out[b][o] = sum_n g[n]*W_o[o][n] + B_o[o]*S, fp64; FLOAT32 output.
__global__ __launch_bounds__(256) void k_memout(
    const double* __restrict__ g, const float* __restrict__ WoT,
    const float* __restrict__ Bo, const float* __restrict__ tau_out,
    float* __restrict__ mout)
{
    __shared__ double gs[NREC];
    const int b = blockIdx.x, tid = threadIdx.x;
#pragma unroll
    for (int k = 0; k < 8; ++k)
        gs[tid + 256 * k] = g[(size_t)b * NREC + tid + 256 * k];
    const double c = exp(-0.01 / (double)tau_out[0]);
    double S = 0.0;
    for (int t = 0; t < TT; ++t) S = S * c + 1.0;   // sum_{k=0}^{249} c^k
    __syncthreads();
    if (tid < NOUT) {
        double a = 0.0;
        for (int n = 0; n < NREC; ++n)
            a += gs[n] * (double)WoT[n * NOUT + tid];
        a += (double)Bo[tid] * S;
        mout[(size_t)b * NOUT + tid] = (float)a;
    }
}

// Expand bit masks into the FLOAT32 spike raster d_out[b][n][t].
__global__ __launch_bounds__(256) void k_expand(
    const unsigned* __restrict__ spikeMask, float* __restrict__ zout)
{
    const int bid = blockIdx.x;           // 64 b * 64 word-groups
    const int b = bid >> 6, gw = bid & 63;
    const int t = threadIdx.x;
    if (t >= TT) return;
    const unsigned v = spikeMask[((size_t)(t * BB + b)) * 64 + gw];
    for (int j = 0; j < 32; ++j) {
        const int n = gw * 32 + j;
        zout[((size_t)b * NREC + n) * TT + t] = ((v >> j) & 1u) ? 1.0f : 0.0f;
    }
}

extern "C" void kernel_launch(void* const* d_in, const int* in_sizes, int n_in,
                              void* d_out, int out_size, void* d_ws, size_t ws_size,
                              hipStream_t stream) {
    // bind inputs by SIZE (immune to reordering); 4M pair sniffed on-device
    const float *x = nullptr, *Wi = nullptr, *Wo = nullptr, *Br = nullptr, *Bo = nullptr;
    const void* c4[2] = {nullptr, nullptr};
    const float* sc[3] = {nullptr, nullptr, nullptr};
    int n4 = 0, nsc = 0;
    for (int i = 0; i < n_in; ++i) {
        switch (in_sizes[i]) {
            case 8192000: x  = (const float*)d_in[i]; break;
            case 1048576: Wi = (const float*)d_in[i]; break;
            case 262144:  Wo = (const float*)d_in[i]; break;
            case 2048:    Br = (const float*)d_in[i]; break;
            case 128:     Bo = (const float*)d_in[i]; break;
            case 4194304: if (n4 < 2)  c4[n4++]  = d_in[i]; break;
            case 1:       if (nsc < 3) sc[nsc++] = (const float*)d_in[i]; break;
            default: break;
        }
    }
    if (!x || !Wi || !Wo || !Br || !Bo || n4 < 2 || nsc < 3) {
        x  = (const float*)d_in[0];
        c4[0] = d_in[1];
        Wi = (const float*)d_in[2];
        c4[1] = d_in[3];
        Wo = (const float*)d_in[4];
        Br = (const float*)d_in[5];
        Bo = (const float*)d_in[6];
        sc[0] = (const float*)d_in[7];
        sc[1] = (const float*)d_in[8];
        sc[2] = (const float*)d_in[9];
    }
    // dict order: sc = {tau_rec, tau_out, thr_rec}
    const float* taur = sc[0];
    const float* tauo = sc[1];
    const float* thr  = sc[2];

    float* out = (float*)d_out;                       // FLOAT32 outputs
    char* ws = (char*)d_ws;
    float*          WrT  = (float*)(ws + OFF_WRT);
    unsigned char*  dBp  = (unsigned char*)(ws + OFF_DB);
    float*          WiT  = (float*)(ws + OFF_WIT);
    float*          WoT  = (float*)(ws + OFF_WOT);
    unsigned*       mask = (unsigned*)(ws + OFF_MASK);
    double*         g    = (double*)(ws + OFF_G);

    hipLaunchKernelGGL(k_prep, dim3((NREC * NREC + 255) / 256), dim3(256), 0, stream,
                       c4[0], c4[1], Wi, Wo, WrT, dBp, WiT, WoT);
    hipLaunchKernelGGL(k_main, dim3(BB), dim3(1024), 0, stream,
                       x, WrT, dBp, WiT, Br, taur, tauo, thr, mask, g);
    hipLaunchKernelGGL(k_memout, dim3(BB), dim3(256), 0, stream,
                       g, WoT, Bo, tauo, out);
    hipLaunchKernelGGL(k_expand, dim3(BB * 64), dim3(256), 0, stream,
                       mask, out + 8192);
}

// Round 11
// 7203.067 us; speedup vs baseline: 1.5295x; 1.5295x over previous
//
#include <hip/hip_runtime.h>

#define NIN  512
#define NREC 2048
#define NOUT 128
#define BB   64
#define TT   250

// OUTPUTS ARE FLOAT32 (established R9 probe). Semantics: JAX text (verified R10 PASS).
// ---- d_ws layout (31.4 MB total; 34.5 MB verified safe) ----
#define OFF_WRT  0UL          // f32 W_r^T [n][m]      16,777,216
#define OFF_DB   16777216UL   // u8  delays [n][m]      4,194,304
#define OFF_WIT  20971520UL   // f32 W_i^T [i][m]       4,194,304
#define OFF_WOT  25165824UL   // f32 W_o^T [n][o]       1,048,576
#define OFF_MASK 26214400UL   // u32 masks [t*64+b][64] 4,096,000
#define OFF_G    30310400UL   // f64 g[b][n]            1,048,576

__device__ __forceinline__ int decode_delay(int v) {
    if (v >= 0 && v <= 4) return v;
    const float f = __int_as_float(v);
    if (f >= 0.5f && f <= 4.5f) return (int)(f + 0.5f);
    return 0;
}
__device__ __forceinline__ int delay_like(int v) {
    if (v >= 0 && v <= 4) return 1;
    const float f = __int_as_float(v);
    return (f >= 0.5f && f <= 4.5f) ? 1 : 0;
}
__device__ __forceinline__ unsigned lane_rank(unsigned long long m) {
    unsigned r = __builtin_amdgcn_mbcnt_lo((unsigned)m, 0u);
    return __builtin_amdgcn_mbcnt_hi((unsigned)(m >> 32), r);
}

// Stage transposed weights + packed delays (sniffs delays vs W_r). Verified R6/R10.
__global__ __launch_bounds__(256) void k_prep(
    const void* __restrict__ c4A, const void* __restrict__ c4B,
    const float* __restrict__ Wi, const float* __restrict__ Wo,
    float* __restrict__ WrT, unsigned char* __restrict__ dBp,
    float* __restrict__ WiT, float* __restrict__ WoT)
{
    const int* iA = (const int*)c4A;
    const int* iB = (const int*)c4B;
    int cntA = 0, cntB = 0;
    for (int j = 0; j < 64; ++j) { cntA += delay_like(iA[j]); cntB += delay_like(iB[j]); }
    const int*   dl = (cntA >= cntB) ? iA : iB;
    const float* Wr = (cntA >= cntB) ? (const float*)c4B : (const float*)c4A;

    const int idx = blockIdx.x * 256 + threadIdx.x;
    if (idx < NREC * NREC) {
        const int n = idx >> 11, m = idx & 2047;
        WrT[idx] = Wr[(size_t)m * NREC + n];                 // W_rT[n][m] = W_r[m][n]
        dBp[idx] = (unsigned char)decode_delay(dl[idx]);     // delays[n][m] natural
    }
    if (idx < NIN * NREC) {
        const int i = idx >> 11, m = idx & 2047;
        WiT[idx] = Wi[(size_t)m * NIN + i];                  // W_iT[i][m]
    }
    if (idx < NREC * NOUT) {
        const int n = idx >> 7, o = idx & 127;
        WoT[idx] = Wo[(size_t)o * NREC + n];                 // W_oT[n][o]
    }
}

// Main recurrence, FP64, one block per batch, 1024 threads x 2 neurons.
// R11: event loops restructured as LDS index lists + unroll-4 pipelines
// (4 weight rows in flight) to break the one-row-at-a-time latency chain.
// List construction is deterministic (wave popc -> prefix -> mbcnt rank).
__global__ __launch_bounds__(1024) void k_main(
    const float* __restrict__ x,
    const float* __restrict__ WrT, const unsigned char* __restrict__ dBp,
    const float* __restrict__ WiT,
    const float* __restrict__ Br,
    const float* __restrict__ tau_rec, const float* __restrict__ tau_out,
    const float* __restrict__ thr_rec,
    unsigned* __restrict__ spikeMask, double* __restrict__ g)
{
    __shared__ int icnt[8];                 // input-spike counts per wave (waves 0-7)
    __shared__ unsigned short ilist[NIN];   // active input channels, ascending
    __shared__ int zcnt[32];                // [0..15]=A-half, [16..31]=B-half counts
    __shared__ unsigned short slist[NREC];  // spiking neurons, ascending

    const int b    = blockIdx.x;
    const int tid  = threadIdx.x;
    const int w    = tid >> 6;
    const int lane = tid & 63;

    const double rec_c = exp(-0.01 / (double)tau_rec[0]);
    const double out_c = exp(-0.01 / (double)tau_out[0]);
    const double thr   = (double)thr_rec[0];
    const double brA   = (double)Br[tid];
    const double brB   = (double)Br[tid + 1024];
    double memA = 0.0, memB = 0.0, gA = 0.0, gB = 0.0;
    double a0 = 0.0, a1 = 0.0, a2 = 0.0, a3 = 0.0;   // ring, neuron tid
    double c0 = 0.0, c1 = 0.0, c2 = 0.0, c3 = 0.0;   // ring, neuron tid+1024

    const float* xb = x + (size_t)b * NIN * TT;      // x[b][i][t]
    float xv = (tid < NIN) ? xb[(size_t)tid * TT] : 0.f;   // prefetched x(t)

    for (int t = 0; t < TT; ++t) {
        // consume current scheduled for this step, rotate ring
        double curA = a0; a0 = a1; a1 = a2; a2 = a3; a3 = 0.0;
        double curB = c0; c0 = c1; c1 = c2; c2 = c3; c3 = 0.0;

        // ---- input spike ballot + counts ----
        unsigned long long im = 0;
        bool ihit = false;
        if (w < 8) {
            ihit = (xv != 0.f);
            im = __ballot(ihit);
            if (lane == 0) icnt[w] = __popcll(im);
        }
        // prefetch next step's x element (hides the strided x read)
        float xv_next = 0.f;
        if (t + 1 < TT && tid < NIN) xv_next = xb[(size_t)tid * TT + (t + 1)];
        __syncthreads();                                  // S1: icnt ready; prev scatter done

        // ---- build input list (deterministic, ascending) ----
        int ioffw = 0, itot = 0;
        for (int j = 0; j < 8; ++j) { const int c = icnt[j]; if (j < w) ioffw += c; itot += c; }
        if (ihit) ilist[ioffw + lane_rank(im)] = (unsigned short)tid;
        __syncthreads();                                  // S2: ilist ready

        // ---- pipelined input gather (4 rows in flight) ----
        {
            int k = 0;
            for (; k + 4 <= itot; k += 4) {
                const int i0 = ilist[k], i1 = ilist[k + 1], i2 = ilist[k + 2], i3 = ilist[k + 3];
                const float* r0 = WiT + (size_t)i0 * NREC;
                const float* r1 = WiT + (size_t)i1 * NREC;
                const float* r2 = WiT + (size_t)i2 * NREC;
                const float* r3 = WiT + (size_t)i3 * NREC;
                const float A0 = r0[tid], B0 = r0[tid + 1024];
                const float A1 = r1[tid], B1 = r1[tid + 1024];
                const float A2 = r2[tid], B2 = r2[tid + 1024];
                const float A3 = r3[tid], B3 = r3[tid + 1024];
                curA += (double)A0; curA += (double)A1; curA += (double)A2; curA += (double)A3;
                curB += (double)B0; curB += (double)B1; curB += (double)B2; curB += (double)B3;
            }
            for (; k < itot; ++k) {
                const float* r0 = WiT + (size_t)ilist[k] * NREC;
                curA += (double)r0[tid];
                curB += (double)r0[tid + 1024];
            }
        }
        curA += brA; curB += brB;

        // ---- LIF update + spike + soft reset ----
        memA = memA * rec_c + curA;
        memB = memB * rec_c + curB;
        const bool zA = (memA - thr) > 0.0;
        const bool zB = (memB - thr) > 0.0;
        if (zA) memA -= thr;
        if (zB) memB -= thr;
        gA = gA * out_c + (zA ? 1.0 : 0.0);
        gB = gB * out_c + (zB ? 1.0 : 0.0);

        // ---- spike ballot, counts, global mask publish ----
        const unsigned long long mA = __ballot(zA);
        const unsigned long long mB = __ballot(zB);
        if (lane == 0) {
            zcnt[w]      = __popcll(mA);
            zcnt[16 + w] = __popcll(mB);
            unsigned* gm = spikeMask + (size_t)(t * BB + b) * 64;
            gm[2 * w]          = (unsigned)(mA & 0xFFFFFFFFu);
            gm[2 * w + 1]      = (unsigned)(mA >> 32);
            gm[32 + 2 * w]     = (unsigned)(mB & 0xFFFFFFFFu);
            gm[32 + 2 * w + 1] = (unsigned)(mB >> 32);
        }
        xv = xv_next;
        __syncthreads();                                  // S3: zcnt ready

        // ---- build spike list (deterministic, ascending) ----
        int offA = 0, offB = 0, stot = 0;
        for (int j = 0; j < 32; ++j) {
            const int c = zcnt[j];
            if (j < w)      offA += c;
            if (j < 16 + w) offB += c;
            stot += c;
        }
        if (zA) slist[offA + lane_rank(mA)] = (unsigned short)tid;
        if (zB) slist[offB + lane_rank(mB)] = (unsigned short)(tid + 1024);
        __syncthreads();                                  // S4: slist ready

        // ---- pipelined scatter (4 rows in flight); t>0 gate drops t=0 spikes ----
        if (t > 0) {
            int k = 0;
            for (; k + 4 <= stot; k += 4) {
                const int n0 = slist[k], n1 = slist[k + 1], n2 = slist[k + 2], n3 = slist[k + 3];
                const size_t r0 = (size_t)n0 * NREC, r1 = (size_t)n1 * NREC;
                const size_t r2 = (size_t)n2 * NREC, r3 = (size_t)n3 * NREC;
                const float wA0 = WrT[r0 + tid], wB0 = WrT[r0 + tid + 1024];
                const float wA1 = WrT[r1 + tid], wB1 = WrT[r1 + tid + 1024];
                const float wA2 = WrT[r2 + tid], wB2 = WrT[r2 + tid + 1024];
                const float wA3 = WrT[r3 + tid], wB3 = WrT[r3 + tid + 1024];
                const int dA0 = dBp[r0 + tid], dB0 = dBp[r0 + tid + 1024];
                const int dA1 = dBp[r1 + tid], dB1 = dBp[r1 + tid + 1024];
                const int dA2 = dBp[r2 + tid], dB2 = dBp[r2 + tid + 1024];
                const int dA3 = dBp[r3 + tid], dB3 = dBp[r3 + tid + 1024];
                a0 += (dA0 == 1) ? (double)wA0 : 0.0; a1 += (dA0 == 2) ? (double)wA0 : 0.0;
                a2 += (dA0 == 3) ? (double)wA0 : 0.0; a3 += (dA0 == 4) ? (double)wA0 : 0.0;
                a0 += (dA1 == 1) ? (double)wA1 : 0.0; a1 += (dA1 == 2) ? (double)wA1 : 0.0;
                a2 += (dA1 == 3) ? (double)wA1 : 0.0; a3 += (dA1 == 4) ? (double)wA1 : 0.0;
                a0 += (dA2 == 1) ? (double)wA2 : 0.0; a1 += (dA2 == 2) ? (double)wA2 : 0.0;
                a2 += (dA2 == 3) ? (double)wA2 : 0.0; a3 += (dA2 == 4) ? (double)wA2 : 0.0;
                a0 += (dA3 == 1) ? (double)wA3 : 0.0; a1 += (dA3 == 2) ? (double)wA3 : 0.0;
                a2 += (dA3 == 3) ? (double)wA3 : 0.0; a3 += (dA3 == 4) ? (double)wA3 : 0.0;
                c0 += (dB0 == 1) ? (double)wB0 : 0.0; c1 += (dB0 == 2) ? (double)wB0 : 0.0;
                c2 += (dB0 == 3) ? (double)wB0 : 0.0; c3 += (dB0 == 4) ? (double)wB0 : 0.0;
                c0 += (dB1 == 1) ? (double)wB1 : 0.0; c1 += (dB1 == 2) ? (double)wB1 : 0.0;
                c2 += (dB1 == 3) ? (double)wB1 : 0.0; c3 += (dB1 == 4) ? (double)wB1 : 0.0;
                c0 += (dB2 == 1) ? (double)wB2 : 0.0; c1 += (dB2 == 2) ? (double)wB2 : 0.0;
                c2 += (dB2 == 3) ? (double)wB2 : 0.0; c3 += (dB2 == 4) ? (double)wB2 : 0.0;
                c0 += (dB3 == 1) ? (double)wB3 : 0.0; c1 += (dB3 == 2) ? (double)wB3 : 0.0;
                c2 += (dB3 == 3) ? (double)wB3 : 0.0; c3 += (dB3 == 4) ? (double)wB3 : 0.0;
            }
            for (; k < stot; ++k) {
                const size_t r0 = (size_t)slist[k] * NREC;
                const float wA = WrT[r0 + tid], wB = WrT[r0 + tid + 1024];
                const int dA = dBp[r0 + tid], dV = dBp[r0 + tid + 1024];
                a0 += (dA == 1) ? (double)wA : 0.0; a1 += (dA == 2) ? (double)wA : 0.0;
                a2 += (dA == 3) ? (double)wA : 0.0; a3 += (dA == 4) ? (double)wA : 0.0;
                c0 += (dV == 1) ? (double)wB : 0.0; c1 += (dV == 2) ? (double)wB : 0.0;
                c2 += (dV == 3) ? (double)wB : 0.0; c3 += (dV == 4) ? (double)wB : 0.0;
            }
        }
        // next iteration's S1 protects the lists before they are rebuilt
    }

    g[(size_t)b * NREC + tid]        = gA;
    g[(size_t)b * NREC + tid + 1024] = gB;
}

// mem_out[b][o] = sum_n g[n]*W_o[o][n] + B_o[o]*S, fp64; FLOAT32 output.
__global__ __launch_bounds__(256) void k_memout(
    const double* __restrict__ g, const float* __restrict__ WoT,
    const float* __restrict__ Bo, const float* __restrict__ tau_out,
    float* __restrict__ mout)
{
    __shared__ double gs[NREC];
    const int b = blockIdx.x, tid = threadIdx.x;
#pragma unroll
    for (int k = 0; k < 8; ++k)
        gs[tid + 256 * k] = g[(size_t)b * NREC + tid + 256 * k];
    const double c = exp(-0.01 / (double)tau_out[0]);
    double S = 0.0;
    for (int t = 0; t < TT; ++t) S = S * c + 1.0;
    __syncthreads();
    if (tid < NOUT) {
        double a = 0.0;
        for (int n = 0; n < NREC; ++n)
            a += gs[n] * (double)WoT[n * NOUT + tid];
        a += (double)Bo[tid] * S;
        mout[(size_t)b * NOUT + tid] = (float)a;
    }
}

// Expand bit masks into the FLOAT32 spike raster d_out[b][n][t].
__global__ __launch_bounds__(256) void k_expand(
    const unsigned* __restrict__ spikeMask, float* __restrict__ zout)
{
    const int bid = blockIdx.x;           // 64 b * 64 word-groups
    const int b = bid >> 6, gw = bid & 63;
    const int t = threadIdx.x;
    if (t >= TT) return;
    const unsigned v = spikeMask[((size_t)(t * BB + b)) * 64 + gw];
    for (int j = 0; j < 32; ++j) {
        const int n = gw * 32 + j;
        zout[((size_t)b * NREC + n) * TT + t] = ((v >> j) & 1u) ? 1.0f : 0.0f;
    }
}

extern "C" void kernel_launch(void* const* d_in, const int* in_sizes, int n_in,
                              void* d_out, int out_size, void* d_ws, size_t ws_size,
                              hipStream_t stream) {
    const float *x = nullptr, *Wi = nullptr, *Wo = nullptr, *Br = nullptr, *Bo = nullptr;
    const void* c4[2] = {nullptr, nullptr};
    const float* sc[3] = {nullptr, nullptr, nullptr};
    int n4 = 0, nsc = 0;
    for (int i = 0; i < n_in; ++i) {
        switch (in_sizes[i]) {
            case 8192000: x  = (const float*)d_in[i]; break;
            case 1048576: Wi = (const float*)d_in[i]; break;
            case 262144:  Wo = (const float*)d_in[i]; break;
            case 2048:    Br = (const float*)d_in[i]; break;
            case 128:     Bo = (const float*)d_in[i]; break;
            case 4194304: if (n4 < 2)  c4[n4++]  = d_in[i]; break;
            case 1:       if (nsc < 3) sc[nsc++] = (const float*)d_in[i]; break;
            default: break;
        }
    }
    if (!x || !Wi || !Wo || !Br || !Bo || n4 < 2 || nsc < 3) {
        x  = (const float*)d_in[0];
        c4[0] = d_in[1];
        Wi = (const float*)d_in[2];
        c4[1] = d_in[3];
        Wo = (const float*)d_in[4];
        Br = (const float*)d_in[5];
        Bo = (const float*)d_in[6];
        sc[0] = (const float*)d_in[7];
        sc[1] = (const float*)d_in[8];
        sc[2] = (const float*)d_in[9];
    }
    const float* taur = sc[0];
    const float* tauo = sc[1];
    const float* thr  = sc[2];

    float* out = (float*)d_out;
    char* ws = (char*)d_ws;
    float*          WrT  = (float*)(ws + OFF_WRT);
    unsigned char*  dBp  = (unsigned char*)(ws + OFF_DB);
    float*          WiT  = (float*)(ws + OFF_WIT);
    float*          WoT  = (float*)(ws + OFF_WOT);
    unsigned*       mask = (unsigned*)(ws + OFF_MASK);
    double*         g    = (double*)(ws + OFF_G);

    hipLaunchKernelGGL(k_prep, dim3((NREC * NREC + 255) / 256), dim3(256), 0, stream,
                       c4[0], c4[1], Wi, Wo, WrT, dBp, WiT, WoT);
    hipLaunchKernelGGL(k_main, dim3(BB), dim3(1024), 0, stream,
                       x, WrT, dBp, WiT, Br, taur, tauo, thr, mask, g);
    hipLaunchKernelGGL(k_memout, dim3(BB), dim3(256), 0, stream,
                       g, WoT, Bo, tauo, out);
    hipLaunchKernelGGL(k_expand, dim3(BB * 64), dim3(256), 0, stream,
                       mask, out + 8192);
}